// Round 1
// baseline (3132.237 us; speedup 1.0000x reference)
//
#include <hip/hip_runtime.h>

#define NTHR 128
#define ROWLEN 100   // floats per thread row; 400B, 16B-aligned, conflict-free b128 pattern

__device__ __forceinline__ void mm3(const float* A, const float* Bm, float* C) {
  #pragma unroll
  for (int i = 0; i < 3; ++i) {
    #pragma unroll
    for (int j = 0; j < 3; ++j) {
      C[i*3+j] = fmaf(A[i*3+0], Bm[0*3+j], fmaf(A[i*3+1], Bm[1*3+j], A[i*3+2]*Bm[2*3+j]));
    }
  }
}

// Middle layer: LDS row -> regs -> (j-tiled) -> LDS row (in place).
// xr static (k fully unrolled), acc static (jj fully unrolled), jt runtime (LDS addr + uniform W offset ok).
template<int K, int N>
__device__ __forceinline__ void layer_mid(float* row, const float* __restrict__ W,
                                          const float* __restrict__ bias) {
  float xr[K];
  #pragma unroll
  for (int k = 0; k < K; ++k) xr[k] = row[k];
  #pragma unroll 1
  for (int jt = 0; jt < N; jt += 10) {
    float acc[10];
    #pragma unroll
    for (int jj = 0; jj < 10; ++jj) acc[jj] = bias[jt + jj];
    #pragma unroll
    for (int k = 0; k < K; ++k) {
      const float xk = xr[k];
      #pragma unroll
      for (int jj = 0; jj < 10; ++jj)
        acc[jj] = fmaf(xk, W[k*N + jt + jj], acc[jj]);
    }
    #pragma unroll
    for (int jj = 0; jj < 10; ++jj) {
      float a = acc[jj];
      row[jt + jj] = fmaxf(a, 0.1f * a);   // LeakyReLU(0.1)
    }
  }
}

__global__ __launch_bounds__(NTHR)
void tbnn_kernel(const float* __restrict__ s_g, const float* __restrict__ w_g,
                 const float* __restrict__ W0, const float* __restrict__ b0,
                 const float* __restrict__ W1, const float* __restrict__ b1,
                 const float* __restrict__ W2, const float* __restrict__ b2,
                 const float* __restrict__ W3, const float* __restrict__ b3,
                 const float* __restrict__ W4, const float* __restrict__ b4,
                 const float* __restrict__ W5, const float* __restrict__ b5,
                 float* __restrict__ out)
{
  __shared__ float lds[NTHR * ROWLEN];   // 50 KB
  const int tid = threadIdx.x;
  const long b = (long)blockIdx.x * NTHR + tid;
  float* row = &lds[tid * ROWLEN];

  float s[9], w[9];
  {
    const float* sp = s_g + b * 9;
    const float* wp = w_g + b * 9;
    #pragma unroll
    for (int i = 0; i < 9; ++i) s[i] = sp[i];
    #pragma unroll
    for (int i = 0; i < 9; ++i) w[i] = wp[i];
  }

  // ---- invariants [l1..l5] ----
  float x0, x1, x2, x3, x4;
  {
    float s2[9], w2[9];
    mm3(s, s, s2); mm3(w, w, w2);
    x0 = s2[0] + s2[4] + s2[8];
    x1 = w2[0] + w2[4] + w2[8];
    float l3 = 0.f, l4 = 0.f, l5 = 0.f;
    #pragma unroll
    for (int i = 0; i < 3; ++i) {
      #pragma unroll
      for (int j = 0; j < 3; ++j) {
        l3 = fmaf(s2[i*3+j], s[j*3+i], l3);   // tr(s2 @ s)
        l4 = fmaf(w2[i*3+j], s[j*3+i], l4);   // tr(w2 @ s)
        l5 = fmaf(w2[i*3+j], s2[j*3+i], l5);  // tr(w2 @ s2)
      }
    }
    x2 = l3; x3 = l4; x4 = l5;
  }

  // ---- layer 0: 5 -> 50 (all regs) ----
  float h0[50];
  #pragma unroll
  for (int j = 0; j < 50; ++j) {
    float a = b0[j];
    a = fmaf(x0, W0[j],       a);
    a = fmaf(x1, W0[50 + j],  a);
    a = fmaf(x2, W0[100 + j], a);
    a = fmaf(x3, W0[150 + j], a);
    a = fmaf(x4, W0[200 + j], a);
    h0[j] = fmaxf(a, 0.1f * a);
  }

  // ---- layer 1: 50 -> 100 (regs -> LDS) ----
  #pragma unroll 1
  for (int jt = 0; jt < 100; jt += 10) {
    float acc[10];
    #pragma unroll
    for (int jj = 0; jj < 10; ++jj) acc[jj] = b1[jt + jj];
    #pragma unroll
    for (int k = 0; k < 50; ++k) {
      const float hk = h0[k];
      #pragma unroll
      for (int jj = 0; jj < 10; ++jj)
        acc[jj] = fmaf(hk, W1[k*100 + jt + jj], acc[jj]);
    }
    #pragma unroll
    for (int jj = 0; jj < 10; ++jj) {
      float a = acc[jj];
      row[jt + jj] = fmaxf(a, 0.1f * a);
    }
  }

  // ---- layers 2,3: 100 -> 100 (shared body via rep loop to halve code size) ----
  #pragma unroll 1
  for (int rep = 0; rep < 2; ++rep) {
    layer_mid<100, 100>(row, rep ? W3 : W2, rep ? b3 : b2);
  }
  // ---- layer 4: 100 -> 50 ----
  layer_mid<100, 50>(row, W4, b4);

  // ---- layer 5: 50 -> 10 (linear) ----
  float g[10];
  {
    float xr[50];
    #pragma unroll
    for (int k = 0; k < 50; ++k) xr[k] = row[k];
    #pragma unroll
    for (int j = 0; j < 10; ++j) {
      float a = b5[j];
      #pragma unroll
      for (int k = 0; k < 50; ++k)
        a = fmaf(xr[k], W5[k*10 + j], a);
      g[j] = a;
    }
  }

  // ---- tensor basis accumulation (recompute products; keeps MLP-phase regs low) ----
  float s2[9], w2[9], sw[9], ws[9];
  mm3(s, s, s2); mm3(w, w, w2); mm3(s, w, sw); mm3(w, s, ws);
  const float l1 = s2[0] + s2[4] + s2[8];
  const float l2 = w2[0] + w2[4] + w2[8];

  float Q[9];
  // T1 = s ; T2 = sw - ws
  #pragma unroll
  for (int i = 0; i < 9; ++i)
    Q[i] = fmaf(g[0], s[i], g[1] * (sw[i] - ws[i]));
  // T3 = s2 - l1/3 I ; T4 = w2 - l2/3 I
  #pragma unroll
  for (int i = 0; i < 9; ++i)
    Q[i] = fmaf(g[2], s2[i], fmaf(g[3], w2[i], Q[i]));
  {
    const float c = (g[2]*l1 + g[3]*l2) * (1.f/3.f);
    Q[0] -= c; Q[4] -= c; Q[8] -= c;
  }
  // T5 = w@s2 - s2@w   (keep ws2, s2w for T8/T10)
  float ws2[9], s2w[9];
  mm3(w, s2, ws2); mm3(s2, w, s2w);
  #pragma unroll
  for (int i = 0; i < 9; ++i) Q[i] = fmaf(g[4], ws2[i] - s2w[i], Q[i]);
  // T6 = w2@s + s@w2 - 2/3 tr(s@w2) I
  {
    float w2s[9], sw2[9];
    mm3(w2, s, w2s); mm3(s, w2, sw2);
    const float tr6 = sw2[0] + sw2[4] + sw2[8];
    #pragma unroll
    for (int i = 0; i < 9; ++i) Q[i] = fmaf(g[5], w2s[i] + sw2[i], Q[i]);
    const float c = g[5] * (2.f/3.f) * tr6;
    Q[0] -= c; Q[4] -= c; Q[8] -= c;
  }
  // T7 = ws@w2 - w2@sw
  {
    float t7a[9], t7b[9];
    mm3(ws, w2, t7a); mm3(w2, sw, t7b);
    #pragma unroll
    for (int i = 0; i < 9; ++i) Q[i] = fmaf(g[6], t7a[i] - t7b[i], Q[i]);
  }
  // T8 = sw@s2 - s2@w   (faithful to source)
  {
    float t8a[9];
    mm3(sw, s2, t8a);
    #pragma unroll
    for (int i = 0; i < 9; ++i) Q[i] = fmaf(g[7], t8a[i] - s2w[i], Q[i]);
  }
  // T9 = w2@s2 + s2@w2 - 2/3 tr(s2@w2) I
  {
    float w2s2[9], s2w2[9];
    mm3(w2, s2, w2s2); mm3(s2, w2, s2w2);
    const float tr9 = s2w2[0] + s2w2[4] + s2w2[8];
    #pragma unroll
    for (int i = 0; i < 9; ++i) Q[i] = fmaf(g[8], w2s2[i] + s2w2[i], Q[i]);
    const float c = g[8] * (2.f/3.f) * tr9;
    Q[0] -= c; Q[4] -= c; Q[8] -= c;
  }
  // T10 = (w@s2)@w2 - w2@(s2@w)
  {
    float ta[9], tb[9];
    mm3(ws2, w2, ta); mm3(w2, s2w, tb);
    #pragma unroll
    for (int i = 0; i < 9; ++i) Q[i] = fmaf(g[9], ta[i] - tb[i], Q[i]);
  }

  // deviatoric + normalize
  {
    const float trq = (Q[0] + Q[4] + Q[8]) * (1.f/3.f);
    Q[0] -= trq; Q[4] -= trq; Q[8] -= trq;
  }
  float ssum = 1e-8f;
  #pragma unroll
  for (int i = 0; i < 9; ++i) ssum = fmaf(Q[i], Q[i], ssum);
  const float inv = rsqrtf(ssum);

  float* op = out + b * 9;
  #pragma unroll
  for (int i = 0; i < 9; ++i) op[i] = Q[i] * inv;
}

extern "C" void kernel_launch(void* const* d_in, const int* in_sizes, int n_in,
                              void* d_out, int out_size, void* d_ws, size_t ws_size,
                              hipStream_t stream) {
  const float* s_g = (const float*)d_in[0];
  const float* w_g = (const float*)d_in[1];
  const float* W0 = (const float*)d_in[2];  const float* b0 = (const float*)d_in[3];
  const float* W1 = (const float*)d_in[4];  const float* b1 = (const float*)d_in[5];
  const float* W2 = (const float*)d_in[6];  const float* b2 = (const float*)d_in[7];
  const float* W3 = (const float*)d_in[8];  const float* b3 = (const float*)d_in[9];
  const float* W4 = (const float*)d_in[10]; const float* b4 = (const float*)d_in[11];
  const float* W5 = (const float*)d_in[12]; const float* b5 = (const float*)d_in[13];
  float* out = (float*)d_out;

  const int B = in_sizes[0] / 9;
  const int grid = (B + NTHR - 1) / NTHR;
  hipLaunchKernelGGL(tbnn_kernel, dim3(grid), dim3(NTHR), 0, stream,
                     s_g, w_g, W0, b0, W1, b1, W2, b2, W3, b3, W4, b4, W5, b5, out);
}

// Round 7
// 258.055 us; speedup vs baseline: 12.1379x; 12.1379x over previous
//
#include <hip/hip_runtime.h>
#include <hip/hip_fp16.h>

typedef __attribute__((ext_vector_type(2))) int i32x2;
typedef __attribute__((ext_vector_type(4))) int i32x4;
typedef __attribute__((ext_vector_type(4))) float f32x4;
typedef __attribute__((ext_vector_type(8))) _Float16 half8;
typedef __attribute__((ext_vector_type(2))) __fp16 pkh2;   // return type of cvt_pkrtz

#define NTHR 128          // 2 waves/block, each wave owns 64 rows (4 M-tiles of 16)
#define CHUNKB 4096       // LDS bytes per 16-row chunk: 128 cols * 16 rows * 2B
// LDS activation layout (per block, 32 KB): addr(r, c) = (r>>4)*CHUNKB + c*32 + (r&15)*2
// This makes ds_read_b64_tr_b16 deliver A-fragments and C-writes contiguous 8B.

__device__ __forceinline__ void mm3(const float* A, const float* Bm, float* C) {
  #pragma unroll
  for (int i = 0; i < 3; ++i) {
    #pragma unroll
    for (int j = 0; j < 3; ++j) {
      C[i*3+j] = fmaf(A[i*3+0], Bm[0*3+j], fmaf(A[i*3+1], Bm[1*3+j], A[i*3+2]*Bm[2*3+j]));
    }
  }
}

// ---------------- weight packing pre-kernel ----------------
// Fragment order (fid): L0[0..3] L1[4..17] L2[18..45] L3[46..73] L4[74..89] L5[90..91]
// Within a layer: fid = base + nt*KS + ks.  Fragment = 64 lanes x 8 f16 (16B/lane).
// B-frag layout (16x16x32): lane l, elem e: n = nt*16 + (l&15),
//   k = ks*32 + (l>>4)*4 + (e&3) + (e>>2)*16.  Out-of-range (k>=K || n>=N) -> 0.
// (k-slot convention matches the A-side tr-read exactly; matmul is invariant to
//  any k-permutation applied consistently to BOTH operands.)
__global__ void pack_weights(const float* __restrict__ W0, const float* __restrict__ W1,
                             const float* __restrict__ W2, const float* __restrict__ W3,
                             const float* __restrict__ W4, const float* __restrict__ W5,
                             i32x4* __restrict__ outw)
{
  const int fid = blockIdx.x;
  const int l = threadIdx.x;
  const float* W; int K, N, KS, base;
  if      (fid < 4)  { W = W0; K = 5;   N = 50;  KS = 1; base = 0;  }
  else if (fid < 18) { W = W1; K = 50;  N = 100; KS = 2; base = 4;  }
  else if (fid < 46) { W = W2; K = 100; N = 100; KS = 4; base = 18; }
  else if (fid < 74) { W = W3; K = 100; N = 100; KS = 4; base = 46; }
  else if (fid < 90) { W = W4; K = 100; N = 50;  KS = 4; base = 74; }
  else               { W = W5; K = 50;  N = 10;  KS = 2; base = 90; }
  const int f  = fid - base;
  const int nt = f / KS, ks = f % KS;
  const int n  = nt * 16 + (l & 15);
  const int kb = ks * 32 + ((l >> 4) * 4);
  unsigned u[4];
  #pragma unroll
  for (int e2 = 0; e2 < 4; ++e2) {
    const int ka = kb + (e2 >> 1) * 16 + (e2 & 1) * 2;
    const float v0 = (ka     < K && n < N) ? W[ka * N + n]       : 0.0f;
    const float v1 = (ka + 1 < K && n < N) ? W[(ka + 1) * N + n] : 0.0f;
    const __half h0 = __float2half(v0), h1 = __float2half(v1);
    u[e2] = (unsigned)__half_as_ushort(h0) | ((unsigned)__half_as_ushort(h1) << 16);
  }
  i32x4 v; v.x = (int)u[0]; v.y = (int)u[1]; v.z = (int)u[2]; v.w = (int)u[3];
  outw[fid * 64 + l] = v;
}

// ---------------- fused MLP layer ----------------
template<bool RELU>
__device__ __forceinline__ void store_cfrag(f32x4 c, char* p) {
  float r0 = c.x, r1 = c.y, r2 = c.z, r3 = c.w;
  if (RELU) {
    r0 = fmaxf(r0, 0.1f * r0); r1 = fmaxf(r1, 0.1f * r1);
    r2 = fmaxf(r2, 0.1f * r2); r3 = fmaxf(r3, 0.1f * r3);
  }
  pkh2 p0 = __builtin_amdgcn_cvt_pkrtz(r0, r1);
  pkh2 p1 = __builtin_amdgcn_cvt_pkrtz(r2, r3);
  i32x2 v; v.x = __builtin_bit_cast(int, p0); v.y = __builtin_bit_cast(int, p1);
  *(i32x2*)p = v;
}

// One layer: reads A-frags for 64 rows (4 M-tiles) from LDS via tr-reads (in-place safe:
// all reads complete before any write), MFMAs against global f16 B-frags, writes
// LeakyReLU'd f16 C back to the same LDS tile. No cross-wave sharing -> no barriers.
template<int KS, int NT, bool RELU>
__device__ __forceinline__ void mlp_layer(unsigned abase, char* wrb,
                                          const i32x4* __restrict__ wfrag,
                                          const float* __restrict__ bias,
                                          int Ndim, int lane)
{
  i32x2 alo[4][KS], ahi[4][KS];
  #pragma unroll
  for (int mt = 0; mt < 4; ++mt) {
    #pragma unroll
    for (int ks = 0; ks < KS; ++ks) {
      asm volatile("ds_read_b64_tr_b16 %0, %2 offset:%c3\n\t"
                   "ds_read_b64_tr_b16 %1, %2 offset:%c4"
                   : "=&v"(alo[mt][ks]), "=&v"(ahi[mt][ks])
                   : "v"(abase), "i"(mt * CHUNKB + ks * 1024),
                     "i"(mt * CHUNKB + ks * 1024 + 512)
                   : "memory");
    }
  }
  asm volatile("s_waitcnt lgkmcnt(0)" ::: "memory");
  __builtin_amdgcn_sched_barrier(0);

  half8 a[4][KS];
  #pragma unroll
  for (int mt = 0; mt < 4; ++mt) {
    #pragma unroll
    for (int ks = 0; ks < KS; ++ks) {
      i32x4 t; t.x = alo[mt][ks].x; t.y = alo[mt][ks].y;
      t.z = ahi[mt][ks].x; t.w = ahi[mt][ks].y;
      a[mt][ks] = __builtin_bit_cast(half8, t);
    }
  }

  #pragma unroll 2
  for (int nt = 0; nt < NT; ++nt) {
    const int n = nt * 16 + (lane & 15);
    const float bv = (n < Ndim) ? bias[n] : 0.0f;
    half8 bfr[KS];
    #pragma unroll
    for (int ks = 0; ks < KS; ++ks)
      bfr[ks] = __builtin_bit_cast(half8, wfrag[(nt * KS + ks) * 64 + lane]);
    f32x4 c0, c1, c2, c3;
    c0.x = c0.y = c0.z = c0.w = bv; c1 = c0; c2 = c0; c3 = c0;
    #pragma unroll
    for (int ks = 0; ks < KS; ++ks) {
      c0 = __builtin_amdgcn_mfma_f32_16x16x32_f16(a[0][ks], bfr[ks], c0, 0, 0, 0);
      c1 = __builtin_amdgcn_mfma_f32_16x16x32_f16(a[1][ks], bfr[ks], c1, 0, 0, 0);
      c2 = __builtin_amdgcn_mfma_f32_16x16x32_f16(a[2][ks], bfr[ks], c2, 0, 0, 0);
      c3 = __builtin_amdgcn_mfma_f32_16x16x32_f16(a[3][ks], bfr[ks], c3, 0, 0, 0);
    }
    char* wp = wrb + nt * 512;   // n0*32 bytes
    store_cfrag<RELU>(c0, wp + 0 * CHUNKB);
    store_cfrag<RELU>(c1, wp + 1 * CHUNKB);
    store_cfrag<RELU>(c2, wp + 2 * CHUNKB);
    store_cfrag<RELU>(c3, wp + 3 * CHUNKB);
  }
}

// ---------------- main kernel ----------------
__global__ __launch_bounds__(NTHR, 2)
void tbnn_main(const float* __restrict__ s_g, const float* __restrict__ w_g,
               const float* __restrict__ b0, const float* __restrict__ b1,
               const float* __restrict__ b2, const float* __restrict__ b3,
               const float* __restrict__ b4, const float* __restrict__ b5,
               const i32x4* __restrict__ wfrag, float* __restrict__ out)
{
  __shared__ char lds_b[2 * 16384];   // 32 KB: [8 chunks][128 cols][16 rows] f16
  const int t = threadIdx.x;
  const int lane = t & 63, wv = t >> 6;
  const long b = (long)blockIdx.x * NTHR + t;

  // --- zero padding cols: 0..31 (layer-0 K-pad) and 112..127 (K=100 -> 128 pad) ---
  {
    char* base = lds_b + wv * 16384;
    i32x4 z; z.x = z.y = z.z = z.w = 0;
    #pragma unroll
    for (int c = 0; c < 4; ++c) {
      *(i32x4*)(base + c * CHUNKB + lane * 16) = z;               // cols 0..31
      if (lane < 32)
        *(i32x4*)(base + c * CHUNKB + 3584 + lane * 16) = z;      // cols 112..127
    }
  }

  // --- load s, w; keep in registers through the whole kernel ---
  float s[9], wm[9];
  {
    const float* sp = s_g + b * 9;
    const float* wp = w_g + b * 9;
    #pragma unroll
    for (int i = 0; i < 9; ++i) s[i] = sp[i];
    #pragma unroll
    for (int i = 0; i < 9; ++i) wm[i] = wp[i];
  }

  // --- invariants -> LDS cols 0..4 (f16) ---
  {
    float s2[9], w2[9];
    mm3(s, s, s2); mm3(wm, wm, w2);
    float x0 = s2[0] + s2[4] + s2[8];
    float x1 = w2[0] + w2[4] + w2[8];
    float l3 = 0.f, l4 = 0.f, l5 = 0.f;
    #pragma unroll
    for (int i = 0; i < 3; ++i) {
      #pragma unroll
      for (int j = 0; j < 3; ++j) {
        l3 = fmaf(s2[i*3+j], s[j*3+i], l3);
        l4 = fmaf(w2[i*3+j], s[j*3+i], l4);
        l5 = fmaf(w2[i*3+j], s2[j*3+i], l5);
      }
    }
    char* rp = lds_b + (t >> 4) * CHUNKB + (t & 15) * 2;
    *(__half*)(rp + 0 * 32) = __float2half(x0);
    *(__half*)(rp + 1 * 32) = __float2half(x1);
    *(__half*)(rp + 2 * 32) = __float2half(l3);
    *(__half*)(rp + 3 * 32) = __float2half(l4);
    *(__half*)(rp + 4 * 32) = __float2half(l5);
  }

  // --- MLP: 6 layers of per-wave MFMA (wave owns rows wv*64..wv*64+63) ---
  // tr-read addressing: per-lane addr MUST be base + lane*8 (8 B/lane spans each
  // 16-lane group's 128B window; m162 semantics). Round-5 bug was (lane&15)*2.
  const unsigned ldsu = (unsigned)(size_t)(void*)lds_b;
  const unsigned abase = ldsu + (unsigned)(wv * 16384 + lane * 8);
  char* wrb = lds_b + wv * 16384 + (lane & 15) * 32 + (lane >> 4) * 8;

  mlp_layer<1, 4, true >(abase, wrb, wfrag +  0 * 64, b0, 50,  lane);
  mlp_layer<2, 7, true >(abase, wrb, wfrag +  4 * 64, b1, 100, lane);
  mlp_layer<4, 7, true >(abase, wrb, wfrag + 18 * 64, b2, 100, lane);
  mlp_layer<4, 7, true >(abase, wrb, wfrag + 46 * 64, b3, 100, lane);
  mlp_layer<4, 4, true >(abase, wrb, wfrag + 74 * 64, b4, 50,  lane);
  mlp_layer<2, 1, false>(abase, wrb, wfrag + 90 * 64, b5, 10,  lane);

  // --- read g[0..9] back (f16 -> f32) ---
  float g[10];
  {
    const char* rp = lds_b + (t >> 4) * CHUNKB + (t & 15) * 2;
    #pragma unroll
    for (int j = 0; j < 10; ++j)
      g[j] = __half2float(*(const __half*)(rp + j * 32));
  }

  // --- tensor basis accumulation (fp32, per-thread) ---
  float s2[9], w2[9], sw[9], ws[9];
  mm3(s, s, s2); mm3(wm, wm, w2); mm3(s, wm, sw); mm3(wm, s, ws);
  const float l1 = s2[0] + s2[4] + s2[8];
  const float l2 = w2[0] + w2[4] + w2[8];

  float Q[9];
  #pragma unroll
  for (int i = 0; i < 9; ++i)
    Q[i] = fmaf(g[0], s[i], g[1] * (sw[i] - ws[i]));
  #pragma unroll
  for (int i = 0; i < 9; ++i)
    Q[i] = fmaf(g[2], s2[i], fmaf(g[3], w2[i], Q[i]));
  {
    const float c = (g[2]*l1 + g[3]*l2) * (1.f/3.f);
    Q[0] -= c; Q[4] -= c; Q[8] -= c;
  }
  float ws2[9], s2w[9];
  mm3(wm, s2, ws2); mm3(s2, wm, s2w);
  #pragma unroll
  for (int i = 0; i < 9; ++i) Q[i] = fmaf(g[4], ws2[i] - s2w[i], Q[i]);
  {
    float w2s[9], sw2[9];
    mm3(w2, s, w2s); mm3(s, w2, sw2);
    const float tr6 = sw2[0] + sw2[4] + sw2[8];
    #pragma unroll
    for (int i = 0; i < 9; ++i) Q[i] = fmaf(g[5], w2s[i] + sw2[i], Q[i]);
    const float c = g[5] * (2.f/3.f) * tr6;
    Q[0] -= c; Q[4] -= c; Q[8] -= c;
  }
  {
    float t7a[9], t7b[9];
    mm3(ws, w2, t7a); mm3(w2, sw, t7b);
    #pragma unroll
    for (int i = 0; i < 9; ++i) Q[i] = fmaf(g[6], t7a[i] - t7b[i], Q[i]);
  }
  {
    float t8a[9];
    mm3(sw, s2, t8a);
    #pragma unroll
    for (int i = 0; i < 9; ++i) Q[i] = fmaf(g[7], t8a[i] - s2w[i], Q[i]);
  }
  {
    float w2s2[9], s2w2[9];
    mm3(w2, s2, w2s2); mm3(s2, w2, s2w2);
    const float tr9 = s2w2[0] + s2w2[4] + s2w2[8];
    #pragma unroll
    for (int i = 0; i < 9; ++i) Q[i] = fmaf(g[8], w2s2[i] + s2w2[i], Q[i]);
    const float c = g[8] * (2.f/3.f) * tr9;
    Q[0] -= c; Q[4] -= c; Q[8] -= c;
  }
  {
    float ta[9], tb[9];
    mm3(ws2, w2, ta); mm3(w2, s2w, tb);
    #pragma unroll
    for (int i = 0; i < 9; ++i) Q[i] = fmaf(g[9], ta[i] - tb[i], Q[i]);
  }

  {
    const float trq = (Q[0] + Q[4] + Q[8]) * (1.f/3.f);
    Q[0] -= trq; Q[4] -= trq; Q[8] -= trq;
  }
  float ssum = 1e-8f;
  #pragma unroll
  for (int i = 0; i < 9; ++i) ssum = fmaf(Q[i], Q[i], ssum);
  const float inv = rsqrtf(ssum);

  float* op = out + b * 9;
  #pragma unroll
  for (int i = 0; i < 9; ++i) op[i] = Q[i] * inv;
}

extern "C" void kernel_launch(void* const* d_in, const int* in_sizes, int n_in,
                              void* d_out, int out_size, void* d_ws, size_t ws_size,
                              hipStream_t stream) {
  const float* s_g = (const float*)d_in[0];
  const float* w_g = (const float*)d_in[1];
  const float* W0 = (const float*)d_in[2];  const float* b0 = (const float*)d_in[3];
  const float* W1 = (const float*)d_in[4];  const float* b1 = (const float*)d_in[5];
  const float* W2 = (const float*)d_in[6];  const float* b2 = (const float*)d_in[7];
  const float* W3 = (const float*)d_in[8];  const float* b3 = (const float*)d_in[9];
  const float* W4 = (const float*)d_in[10]; const float* b4 = (const float*)d_in[11];
  const float* W5 = (const float*)d_in[12]; const float* b5 = (const float*)d_in[13];
  float* out = (float*)d_out;

  i32x4* wfrag = (i32x4*)d_ws;   // 92 KiB of f16 B-fragments
  hipLaunchKernelGGL(pack_weights, dim3(92), dim3(64), 0, stream,
                     W0, W1, W2, W3, W4, W5, wfrag);

  const int B = in_sizes[0] / 9;
  const int grid = (B + NTHR - 1) / NTHR;
  hipLaunchKernelGGL(tbnn_main, dim3(grid), dim3(NTHR), 0, stream,
                     s_g, w_g, b0, b1, b2, b3, b4, b5, (const i32x4*)wfrag, out);
}